// Round 1
// baseline (632.360 us; speedup 1.0000x reference)
//
#include <hip/hip_runtime.h>
#include <cstdint>
#include <cstddef>

#define DEVI __device__ __forceinline__

typedef __attribute__((ext_vector_type(8))) short short8;
typedef __attribute__((ext_vector_type(4))) float f32x4;
typedef __bf16 bf16x8 __attribute__((ext_vector_type(8)));

DEVI float sigf(float x) { return 1.0f / (1.0f + __expf(-x)); }
DEVI float tanh_f(float x) { return 2.0f / (1.0f + __expf(-2.0f * x)) - 1.0f; }

DEVI short f2bf(float x) {
    uint32_t u = __builtin_bit_cast(uint32_t, x);
    u += 0x7FFFu + ((u >> 16) & 1u);   // RTNE
    return (short)(u >> 16);
}

DEVI void gload16(const void* g, void* l) {
    __builtin_amdgcn_global_load_lds(
        (const __attribute__((address_space(1))) void*)g,
        (__attribute__((address_space(3))) void*)l, 16, 0, 0);
}

DEVI f32x4 mfma16(short8 a, short8 b, f32x4 c) {
    return __builtin_amdgcn_mfma_f32_16x16x32_bf16(
        __builtin_bit_cast(bf16x8, a), __builtin_bit_cast(bf16x8, b), c, 0, 0, 0);
}

// ---------------- prep kernels ----------------

// Wstk[n][k], n in [0,4096) gate-major (i,f,g,o), k: [0,300)=W_ih, [300,320)=0, [320,1344)=W_hh
__global__ __launch_bounds__(256) void prep_wstk(const float* __restrict__ Wih,
                                                 const float* __restrict__ Whh,
                                                 short* __restrict__ Wstk) {
    int idx = blockIdx.x * 256 + threadIdx.x;
    if (idx >= 4096 * 1344) return;
    int n = idx / 1344, k = idx - n * 1344;
    float v = 0.f;
    if (k < 300) v = Wih[n * 300 + k];
    else if (k >= 320) v = Whh[n * 1024 + (k - 320)];
    Wstk[idx] = f2bf(v);
}

// x_bf16[t][b][e], e in [0,320), pad 0 beyond 300. q_feats is [B,T,E].
__global__ __launch_bounds__(256) void prep_x(const float* __restrict__ q,
                                              short* __restrict__ xb) {
    int idx = blockIdx.x * 256 + threadIdx.x;
    if (idx >= 14 * 256 * 320) return;
    int t = idx / (256 * 320);
    int r = idx - t * 256 * 320;
    int b = r / 320, e = r - b * 320;
    xb[idx] = (e < 300) ? f2bf(q[(b * 14 + t) * 300 + e]) : (short)0;
}

// Wcat[n'][k], n' in [0,1024): hg=n'>>5, which=(n'>>4)&1, h=hg*16+(n'&15).
// which=0 -> W_w row h, which=1 -> Wp_w row h. k in [0,3072).
__global__ __launch_bounds__(256) void prep_wcat(const float* __restrict__ Ww,
                                                 const float* __restrict__ Wpw,
                                                 short* __restrict__ Wcat) {
    int idx = blockIdx.x * 256 + threadIdx.x;
    if (idx >= 1024 * 3072) return;
    int n = idx / 3072, k = idx - n * 3072;
    int hg = n >> 5, which = (n >> 4) & 1, hl = n & 15;
    int h = hg * 16 + hl;
    const float* src = which ? Wpw : Ww;
    Wcat[idx] = f2bf(src[h * 3072 + k]);
}

// ---------------- LSTM ----------------

// gates[256][4096] = [x_t | h] @ Wstk^T. Tile 64x64, BK=64, 4 waves (2x2).
__global__ __launch_bounds__(256) void lstm_gemm(const short* __restrict__ xt,   // [256][320]
                                                 const short* __restrict__ hb,   // [256][1024]
                                                 const short* __restrict__ Wstk, // [4096][1344]
                                                 float* __restrict__ gates) {
    __shared__ __attribute__((aligned(16))) short As[64 * 64];
    __shared__ __attribute__((aligned(16))) short Bs[64 * 64];
    const int tid = threadIdx.x, l = tid & 63, w = tid >> 6;
    const int m0 = blockIdx.x * 64;   // gridDim.x = 4
    const int n0 = blockIdx.y * 64;   // gridDim.y = 64
    const int wm = w >> 1, wn = w & 1;

    f32x4 acc[2][2];
    for (int i = 0; i < 2; i++)
        for (int j = 0; j < 2; j++) acc[i][j] = f32x4{0.f, 0.f, 0.f, 0.f};

    for (int kt = 0; kt < 21; ++kt) {
        const int k0 = kt * 64;
        __syncthreads();
        // A: rows m0+r, 64 bf16 each; source chunk swizzled so LDS stays linear.
        for (int i = 0; i < 2; i++) {
            int r = w * 16 + i * 8 + (l >> 3);
            int cs = (l & 7) ^ (r & 7);
            const short* src;
            if (kt < 5) src = xt + (m0 + r) * 320 + (k0 + cs * 8);
            else        src = hb + (m0 + r) * 1024 + (k0 - 320 + cs * 8);
            gload16(src, &As[(w * 16 + i * 8) * 64]);
        }
        for (int i = 0; i < 2; i++) {
            int r = w * 16 + i * 8 + (l >> 3);
            int cs = (l & 7) ^ (r & 7);
            const short* src = Wstk + (size_t)(n0 + r) * 1344 + (k0 + cs * 8);
            gload16(src, &Bs[(w * 16 + i * 8) * 64]);
        }
        __syncthreads();
        for (int ks = 0; ks < 2; ++ks) {
            short8 a[2], b[2];
            for (int mf = 0; mf < 2; ++mf) {
                int m = wm * 32 + mf * 16 + (l & 15);
                int c = (ks * 4 + (l >> 4)) ^ (m & 7);
                a[mf] = *(const short8*)&As[m * 64 + c * 8];
            }
            for (int nf = 0; nf < 2; ++nf) {
                int n = wn * 32 + nf * 16 + (l & 15);
                int c = (ks * 4 + (l >> 4)) ^ (n & 7);
                b[nf] = *(const short8*)&Bs[n * 64 + c * 8];
            }
            for (int mf = 0; mf < 2; ++mf)
                for (int nf = 0; nf < 2; ++nf)
                    acc[mf][nf] = mfma16(a[mf], b[nf], acc[mf][nf]);
        }
    }
    for (int mf = 0; mf < 2; ++mf)
        for (int nf = 0; nf < 2; ++nf)
            for (int rg = 0; rg < 4; ++rg) {
                int row = m0 + wm * 32 + mf * 16 + (l >> 4) * 4 + rg;
                int col = n0 + wn * 32 + nf * 16 + (l & 15);
                gates[(size_t)row * 4096 + col] = acc[mf][nf][rg];
            }
}

__global__ __launch_bounds__(256) void lstm_cell(const float* __restrict__ gates,
                                                 const float* __restrict__ bih,
                                                 const float* __restrict__ bhh,
                                                 float* __restrict__ c,
                                                 short* __restrict__ hb) {
    int idx = blockIdx.x * 256 + threadIdx.x;  // 256*1024
    int b = idx >> 10, h = idx & 1023;
    const float* g = gates + (size_t)b * 4096;
    float ig = g[h]        + bih[h]        + bhh[h];
    float fg = g[1024 + h] + bih[1024 + h] + bhh[1024 + h];
    float gg = g[2048 + h] + bih[2048 + h] + bhh[2048 + h];
    float og = g[3072 + h] + bih[3072 + h] + bhh[3072 + h];
    float cn = sigf(fg) * c[idx] + sigf(ig) * tanh_f(gg);
    c[idx] = cn;
    hb[idx] = f2bf(sigf(og) * tanh_f(cn));
}

// ---------------- gated MLP ----------------

// Tile 128x128, BK=64, 4 waves (2x2), each wave 64x64 (acc[4][4]).
// A[m][k]: k<2048 -> box_feats (f32, reg-staged to bf16), k>=2048 -> h[b=m/100][k-2048].
// Epilogue: si = tanh(y+Wb)*sig(g+Wpb), partial logit = si*f_w[h]; lane-reduce; atomicAdd.
__global__ __launch_bounds__(256) void mlp_gemm(const float* __restrict__ box,  // [25600][2048]
                                                const short* __restrict__ hb,   // [256][1024]
                                                const short* __restrict__ Wcat, // [1024][3072]
                                                const float* __restrict__ Wb,
                                                const float* __restrict__ Wpb,
                                                const float* __restrict__ fw,
                                                float* __restrict__ logits) {
    __shared__ __attribute__((aligned(16))) short As[128 * 64];
    __shared__ __attribute__((aligned(16))) short Bs[128 * 64];
    const int tid = threadIdx.x, l = tid & 63, w = tid >> 6;
    const int n0 = blockIdx.x * 128;  // gridDim.x = 8   (fast-varying: A-panel L2 reuse)
    const int m0 = blockIdx.y * 128;  // gridDim.y = 200
    const int wm = w >> 1, wn = w & 1;

    f32x4 acc[4][4];
    for (int i = 0; i < 4; i++)
        for (int j = 0; j < 4; j++) acc[i][j] = f32x4{0.f, 0.f, 0.f, 0.f};

    for (int kt = 0; kt < 48; ++kt) {
        const int k0 = kt * 64;
        __syncthreads();
        if (kt < 32) {
            // box part: load f32, convert, swizzled ds_write
            for (int i = 0; i < 4; i++) {
                int slot = tid + i * 256;        // 128 rows * 8 chunks
                int r = slot >> 3, cc = slot & 7;
                const float* gp = box + (size_t)(m0 + r) * 2048 + (k0 + cc * 8);
                float4 v0 = *(const float4*)gp;
                float4 v1 = *(const float4*)(gp + 4);
                short8 s;
                s[0] = f2bf(v0.x); s[1] = f2bf(v0.y); s[2] = f2bf(v0.z); s[3] = f2bf(v0.w);
                s[4] = f2bf(v1.x); s[5] = f2bf(v1.y); s[6] = f2bf(v1.z); s[7] = f2bf(v1.w);
                *(short8*)&As[r * 64 + ((cc ^ (r & 7)) * 8)] = s;
            }
        } else {
            const int kq = k0 - 2048;
            for (int i = 0; i < 4; i++) {
                int r = w * 32 + i * 8 + (l >> 3);
                int cs = (l & 7) ^ (r & 7);
                unsigned m = (unsigned)(m0 + r);
                unsigned b = m / 100u;
                const short* src = hb + b * 1024 + (kq + cs * 8);
                gload16(src, &As[(w * 32 + i * 8) * 64]);
            }
        }
        for (int i = 0; i < 4; i++) {
            int r = w * 32 + i * 8 + (l >> 3);
            int cs = (l & 7) ^ (r & 7);
            const short* src = Wcat + (size_t)(n0 + r) * 3072 + (k0 + cs * 8);
            gload16(src, &Bs[(w * 32 + i * 8) * 64]);
        }
        __syncthreads();
        for (int ks = 0; ks < 2; ++ks) {
            short8 a[4], b[4];
            for (int mf = 0; mf < 4; ++mf) {
                int m = wm * 64 + mf * 16 + (l & 15);
                int c = (ks * 4 + (l >> 4)) ^ (m & 7);
                a[mf] = *(const short8*)&As[m * 64 + c * 8];
            }
            for (int nf = 0; nf < 4; ++nf) {
                int n = wn * 64 + nf * 16 + (l & 15);
                int c = (ks * 4 + (l >> 4)) ^ (n & 7);
                b[nf] = *(const short8*)&Bs[n * 64 + c * 8];
            }
            for (int mf = 0; mf < 4; ++mf)
                for (int nf = 0; nf < 4; ++nf)
                    acc[mf][nf] = mfma16(a[mf], b[nf], acc[mf][nf]);
        }
    }

    const int hl = l & 15, hi = l >> 4;
    for (int mf = 0; mf < 4; ++mf) {
        float part[4] = {0.f, 0.f, 0.f, 0.f};
        for (int p = 0; p < 2; ++p) {
            int ntg = (n0 + wn * 64) / 16 + 2 * p;  // even: which=0 frag; +1: which=1
            int hg = ntg >> 1;
            int h = hg * 16 + hl;
            float fwv = fw[h], wbv = Wb[h], wpbv = Wpb[h];
            for (int rg = 0; rg < 4; ++rg) {
                float y = tanh_f(acc[mf][2 * p][rg] + wbv);
                float g = sigf(acc[mf][2 * p + 1][rg] + wpbv);
                part[rg] += y * g * fwv;
            }
        }
        for (int rg = 0; rg < 4; ++rg) {
            float v = part[rg];
            v += __shfl_xor(v, 1, 64);
            v += __shfl_xor(v, 2, 64);
            v += __shfl_xor(v, 4, 64);
            v += __shfl_xor(v, 8, 64);
            if (hl == 0) {
                int row = m0 + wm * 64 + mf * 16 + hi * 4 + rg;
                atomicAdd(&logits[row], v);
            }
        }
    }
}

__global__ __launch_bounds__(128) void reduce_out(const float* __restrict__ logits,
                                                  const int* __restrict__ index,
                                                  float* __restrict__ out) {
    int b = blockIdx.x, t = threadIdx.x;
    int idx = index[b];
    float v = 0.f;
    if (t < 100 && t < idx) v = sigf(logits[b * 100 + t]);
    for (int m = 32; m; m >>= 1) v += __shfl_down(v, m, 64);
    __shared__ float s[2];
    if ((t & 63) == 0) s[t >> 6] = v;
    __syncthreads();
    if (t == 0) out[b] = s[0] + s[1];
}

// ---------------- host ----------------

extern "C" void kernel_launch(void* const* d_in, const int* in_sizes, int n_in,
                              void* d_out, int out_size, void* d_ws, size_t ws_size,
                              hipStream_t stream) {
    (void)in_sizes; (void)n_in; (void)out_size; (void)ws_size;
    const float* box = (const float*)d_in[2];
    const float* qf  = (const float*)d_in[3];
    const int* index = (const int*)d_in[5];
    const float* Wih = (const float*)d_in[6];
    const float* Whh = (const float*)d_in[7];
    const float* bih = (const float*)d_in[8];
    const float* bhh = (const float*)d_in[9];
    const float* Ww  = (const float*)d_in[10];
    const float* Wb  = (const float*)d_in[11];
    const float* Wpw = (const float*)d_in[12];
    const float* Wpb = (const float*)d_in[13];
    const float* fw  = (const float*)d_in[14];

    char* p = (char*)d_ws;
    short* Wstk = (short*)p;  p += (size_t)4096 * 1344 * 2;
    short* Wcat = (short*)p;  p += (size_t)1024 * 3072 * 2;
    short* xb   = (short*)p;  p += (size_t)14 * 256 * 320 * 2;
    short* hb   = (short*)p;  p += (size_t)256 * 1024 * 2;
    float* c    = (float*)p;  p += (size_t)256 * 1024 * 4;
    float* gts  = (float*)p;  p += (size_t)256 * 4096 * 4;
    float* lgt  = (float*)p;  p += (size_t)25600 * 4;

    hipMemsetAsync(hb, 0, (size_t)256 * 1024 * 2, stream);
    hipMemsetAsync(c, 0, (size_t)256 * 1024 * 4, stream);
    hipMemsetAsync(lgt, 0, (size_t)25600 * 4, stream);

    prep_wstk<<<(4096 * 1344) / 256, 256, 0, stream>>>(Wih, Whh, Wstk);
    prep_x<<<(14 * 256 * 320) / 256, 256, 0, stream>>>(qf, xb);
    prep_wcat<<<(1024 * 3072) / 256, 256, 0, stream>>>(Ww, Wpw, Wcat);

    for (int t = 0; t < 14; ++t) {
        lstm_gemm<<<dim3(4, 64), 256, 0, stream>>>(xb + (size_t)t * 256 * 320, hb, Wstk, gts);
        lstm_cell<<<1024, 256, 0, stream>>>(gts, bih, bhh, c, hb);
    }

    mlp_gemm<<<dim3(8, 200), 256, 0, stream>>>(box, hb, Wcat, Wb, Wpb, fw, lgt);
    reduce_out<<<256, 128, 0, stream>>>(lgt, index, (float*)d_out);
}

// Round 2
// 622.542 us; speedup vs baseline: 1.0158x; 1.0158x over previous
//
#include <hip/hip_runtime.h>
#include <cstdint>
#include <cstddef>

#define DEVI __device__ __forceinline__

typedef __attribute__((ext_vector_type(8))) short short8;
typedef __attribute__((ext_vector_type(4))) float f32x4;
typedef __bf16 bf16x8 __attribute__((ext_vector_type(8)));

DEVI float sigf(float x) { return 1.0f / (1.0f + __expf(-x)); }
DEVI float tanh_f(float x) { return 2.0f / (1.0f + __expf(-2.0f * x)) - 1.0f; }

DEVI short f2bf(float x) {
    uint32_t u = __builtin_bit_cast(uint32_t, x);
    u += 0x7FFFu + ((u >> 16) & 1u);   // RTNE
    return (short)(u >> 16);
}

DEVI void gload16(const void* g, void* l) {
    __builtin_amdgcn_global_load_lds(
        (const __attribute__((address_space(1))) void*)g,
        (__attribute__((address_space(3))) void*)l, 16, 0, 0);
}

DEVI f32x4 mfma16(short8 a, short8 b, f32x4 c) {
    return __builtin_amdgcn_mfma_f32_16x16x32_bf16(
        __builtin_bit_cast(bf16x8, a), __builtin_bit_cast(bf16x8, b), c, 0, 0, 0);
}

// ---------------- prep kernels ----------------

// Wstk[n'][k], n' = hblk*64 + gate*16 + hl  (orig gate row = gate*1024 + hblk*16 + hl)
// k: [0,300)=W_ih, k==300 -> b_ih+b_hh (paired with constant-1.0 x column),
//    (300,320)=0, [320,1344)=W_hh
__global__ __launch_bounds__(256) void prep_wstk(const float* __restrict__ Wih,
                                                 const float* __restrict__ Whh,
                                                 const float* __restrict__ bih,
                                                 const float* __restrict__ bhh,
                                                 short* __restrict__ Wstk) {
    int idx = blockIdx.x * 256 + threadIdx.x;
    if (idx >= 4096 * 1344) return;
    int n = idx / 1344, k = idx - n * 1344;
    int hblk = n >> 6, gate = (n >> 4) & 3, hl = n & 15;
    int on = gate * 1024 + hblk * 16 + hl;
    float v = 0.f;
    if (k < 300) v = Wih[on * 300 + k];
    else if (k == 300) v = bih[on] + bhh[on];
    else if (k >= 320) v = Whh[on * 1024 + (k - 320)];
    Wstk[idx] = f2bf(v);
}

// x_bf16[t][b][e], e in [0,320): e<300 -> q, e==300 -> 1.0 (bias), else 0.
__global__ __launch_bounds__(256) void prep_x(const float* __restrict__ q,
                                              short* __restrict__ xb) {
    int idx = blockIdx.x * 256 + threadIdx.x;
    if (idx >= 14 * 256 * 320) return;
    int t = idx / (256 * 320);
    int r = idx - t * 256 * 320;
    int b = r / 320, e = r - b * 320;
    float v = (e < 300) ? q[(b * 14 + t) * 300 + e] : (e == 300 ? 1.0f : 0.0f);
    xb[idx] = f2bf(v);
}

// Wcat[n'][k], n' in [0,1024): hg=n'>>5, which=(n'>>4)&1, h=hg*16+(n'&15).
__global__ __launch_bounds__(256) void prep_wcat(const float* __restrict__ Ww,
                                                 const float* __restrict__ Wpw,
                                                 short* __restrict__ Wcat) {
    int idx = blockIdx.x * 256 + threadIdx.x;
    if (idx >= 1024 * 3072) return;
    int n = idx / 3072, k = idx - n * 3072;
    int hg = n >> 5, which = (n >> 4) & 1, hl = n & 15;
    int h = hg * 16 + hl;
    const float* src = which ? Wpw : Ww;
    Wcat[idx] = f2bf(src[h * 3072 + k]);
}

// ---------------- fused LSTM step ----------------

// One timestep: gates = [x_t | h_in] @ Wstk^T, then cell update fused in epilogue.
// Tile 64x64, BK=64, 4 waves; wave w owns rows m0+w*16..+15, all 64 cols (4 gates x 16 h).
__global__ __launch_bounds__(256) void lstm_step(const short* __restrict__ xt,   // [256][320]
                                                 const short* __restrict__ hin,  // [256][1024]
                                                 const short* __restrict__ Wstk, // [4096][1344]
                                                 float* __restrict__ c,          // [256][1024]
                                                 short* __restrict__ hout) {
    __shared__ __attribute__((aligned(16))) short As[64 * 64];
    __shared__ __attribute__((aligned(16))) short Bs[64 * 64];
    const int tid = threadIdx.x, l = tid & 63, w = tid >> 6;
    const int m0 = blockIdx.x * 64;   // gridDim.x = 4
    const int n0 = blockIdx.y * 64;   // gridDim.y = 64

    f32x4 acc[4];
    for (int i = 0; i < 4; i++) acc[i] = f32x4{0.f, 0.f, 0.f, 0.f};

    for (int kt = 0; kt < 21; ++kt) {
        const int k0 = kt * 64;
        __syncthreads();
        for (int i = 0; i < 2; i++) {
            int r = w * 16 + i * 8 + (l >> 3);
            int cs = (l & 7) ^ (r & 7);
            const short* src;
            if (kt < 5) src = xt + (m0 + r) * 320 + (k0 + cs * 8);
            else        src = hin + (m0 + r) * 1024 + (k0 - 320 + cs * 8);
            gload16(src, &As[(w * 16 + i * 8) * 64]);
        }
        for (int i = 0; i < 2; i++) {
            int r = w * 16 + i * 8 + (l >> 3);
            int cs = (l & 7) ^ (r & 7);
            const short* src = Wstk + (size_t)(n0 + r) * 1344 + (k0 + cs * 8);
            gload16(src, &Bs[(w * 16 + i * 8) * 64]);
        }
        __syncthreads();
        for (int ks = 0; ks < 2; ++ks) {
            int m = w * 16 + (l & 15);
            int ca = (ks * 4 + (l >> 4)) ^ (m & 7);
            short8 a = *(const short8*)&As[m * 64 + ca * 8];
            for (int nf = 0; nf < 4; ++nf) {
                int n = nf * 16 + (l & 15);
                int cb = (ks * 4 + (l >> 4)) ^ (n & 7);
                short8 b = *(const short8*)&Bs[n * 64 + cb * 8];
                acc[nf] = mfma16(a, b, acc[nf]);
            }
        }
    }
    // epilogue: nf = gate (0:i 1:f 2:g 3:o), h = (n0/4) + (l&15)
    const int hl = l & 15, hi = l >> 4;
    const int h = (n0 >> 2) + hl;
    for (int rg = 0; rg < 4; ++rg) {
        int row = m0 + w * 16 + hi * 4 + rg;
        float ig = acc[0][rg], fg = acc[1][rg], gg = acc[2][rg], og = acc[3][rg];
        size_t off = (size_t)row * 1024 + h;
        float cn = sigf(fg) * c[off] + sigf(ig) * tanh_f(gg);
        c[off] = cn;
        hout[off] = f2bf(sigf(og) * tanh_f(cn));
    }
}

// ---------------- gated MLP ----------------

// Tile 128x128, BK=64, 4 waves (2x2), wave 64x64 (acc[4][4]).
// 1D grid 1600, XCD-chunked swizzle. Dead rows (j >= index[b]) get clamped loads
// and whole-frag MFMA skip; their logits are garbage but masked in reduce_out.
__global__ __launch_bounds__(256) void mlp_gemm(const float* __restrict__ box,  // [25600][2048] f32
                                                const short* __restrict__ hb,   // [256][1024]
                                                const short* __restrict__ Wcat, // [1024][3072]
                                                const int* __restrict__ index,
                                                const float* __restrict__ Wb,
                                                const float* __restrict__ Wpb,
                                                const float* __restrict__ fw,
                                                float* __restrict__ logits) {
    __shared__ __attribute__((aligned(16))) short As[128 * 64];
    __shared__ __attribute__((aligned(16))) short Bs[128 * 64];
    const int tid = threadIdx.x, l = tid & 63, w = tid >> 6;
    // XCD-chunk swizzle: all 8 n-blocks of one m-panel -> same XCD, adjacent slots
    const int bid = blockIdx.x;              // 1600
    const int xcd = bid & 7, ii = bid >> 3;  // ii in [0,200)
    const int y = xcd * 25 + (ii >> 3);      // m-panel
    const int x = ii & 7;                    // n-panel
    const int n0 = x * 128, m0 = y * 128;
    const int wm = w >> 1, wn = w & 1;

    // per-thread precomputed A/B source rows (fixed across kt)
    int boxrow[4], boxchunk[4];
    for (int i = 0; i < 4; i++) {
        int slot = tid + i * 256;            // 128 rows * 8 chunks
        int r = slot >> 3, cc = slot & 7;
        int m = m0 + r;
        int b = m / 100, j = m - b * 100;
        if (j >= index[b]) m = b * 100;      // clamp dead rows to a live one
        boxrow[i] = m;
        boxchunk[i] = cc;
    }
    const short* hbsrc[4];
    const short* wsrc[4];
    int acs[4];
    for (int i = 0; i < 4; i++) {
        int r = w * 32 + i * 8 + (l >> 3);
        int cs = (l & 7) ^ (r & 7);
        acs[i] = cs;
        hbsrc[i] = hb + (unsigned)((m0 + r) / 100) * 1024 + cs * 8;
        wsrc[i] = Wcat + (size_t)(n0 + r) * 3072 + cs * 8;
    }
    // frag validity (uniform per wave)
    bool fvalid[4];
    for (int mf = 0; mf < 4; ++mf) {
        int r0 = m0 + wm * 64 + mf * 16;
        bool v = false;
        for (int rr = 0; rr < 16; ++rr) {
            int m = r0 + rr, b = m / 100;
            if (m - b * 100 < index[b]) v = true;
        }
        fvalid[mf] = v;
    }

    f32x4 acc[4][4];
    for (int i = 0; i < 4; i++)
        for (int j = 0; j < 4; j++) acc[i][j] = f32x4{0.f, 0.f, 0.f, 0.f};

    for (int kt = 0; kt < 48; ++kt) {
        const int k0 = kt * 64;
        __syncthreads();
        if (kt < 32) {
            for (int i = 0; i < 4; i++) {
                int slot = tid + i * 256;
                int r = slot >> 3, cc = boxchunk[i];
                const float* gp = box + (size_t)boxrow[i] * 2048 + (k0 + cc * 8);
                float4 v0 = *(const float4*)gp;
                float4 v1 = *(const float4*)(gp + 4);
                short8 s;
                s[0] = f2bf(v0.x); s[1] = f2bf(v0.y); s[2] = f2bf(v0.z); s[3] = f2bf(v0.w);
                s[4] = f2bf(v1.x); s[5] = f2bf(v1.y); s[6] = f2bf(v1.z); s[7] = f2bf(v1.w);
                *(short8*)&As[r * 64 + ((cc ^ (r & 7)) * 8)] = s;
            }
        } else {
            const int kq = k0 - 2048;
            for (int i = 0; i < 4; i++)
                gload16(hbsrc[i] + kq, &As[(w * 32 + i * 8) * 64]);
        }
        for (int i = 0; i < 4; i++)
            gload16(wsrc[i] + k0, &Bs[(w * 32 + i * 8) * 64]);
        __syncthreads();
        for (int ks = 0; ks < 2; ++ks) {
            short8 a[4], b[4];
            for (int nf = 0; nf < 4; ++nf) {
                int n = wn * 64 + nf * 16 + (l & 15);
                int cb = (ks * 4 + (l >> 4)) ^ (n & 7);
                b[nf] = *(const short8*)&Bs[n * 64 + cb * 8];
            }
            for (int mf = 0; mf < 4; ++mf) {
                if (!fvalid[mf]) continue;
                int m = wm * 64 + mf * 16 + (l & 15);
                int ca = (ks * 4 + (l >> 4)) ^ (m & 7);
                a[mf] = *(const short8*)&As[m * 64 + ca * 8];
                for (int nf = 0; nf < 4; ++nf)
                    acc[mf][nf] = mfma16(a[mf], b[nf], acc[mf][nf]);
            }
        }
    }

    const int hl = l & 15, hi = l >> 4;
    for (int mf = 0; mf < 4; ++mf) {
        if (!fvalid[mf]) continue;
        float part[4] = {0.f, 0.f, 0.f, 0.f};
        for (int p = 0; p < 2; ++p) {
            int ntg = (n0 + wn * 64) / 16 + 2 * p;
            int hg = ntg >> 1;
            int h = hg * 16 + hl;
            float fwv = fw[h], wbv = Wb[h], wpbv = Wpb[h];
            for (int rg = 0; rg < 4; ++rg) {
                float y2 = tanh_f(acc[mf][2 * p][rg] + wbv);
                float g2 = sigf(acc[mf][2 * p + 1][rg] + wpbv);
                part[rg] += y2 * g2 * fwv;
            }
        }
        for (int rg = 0; rg < 4; ++rg) {
            float v = part[rg];
            v += __shfl_xor(v, 1, 64);
            v += __shfl_xor(v, 2, 64);
            v += __shfl_xor(v, 4, 64);
            v += __shfl_xor(v, 8, 64);
            if (hl == 0) {
                int row = m0 + wm * 64 + mf * 16 + hi * 4 + rg;
                atomicAdd(&logits[row], v);
            }
        }
    }
}

__global__ __launch_bounds__(128) void reduce_out(const float* __restrict__ logits,
                                                  const int* __restrict__ index,
                                                  float* __restrict__ out) {
    int b = blockIdx.x, t = threadIdx.x;
    int idx = index[b];
    float v = 0.f;
    if (t < 100 && t < idx) v = sigf(logits[b * 100 + t]);
    for (int m = 32; m; m >>= 1) v += __shfl_down(v, m, 64);
    __shared__ float s[2];
    if ((t & 63) == 0) s[t >> 6] = v;
    __syncthreads();
    if (t == 0) out[b] = s[0] + s[1];
}

// ---------------- host ----------------

extern "C" void kernel_launch(void* const* d_in, const int* in_sizes, int n_in,
                              void* d_out, int out_size, void* d_ws, size_t ws_size,
                              hipStream_t stream) {
    (void)in_sizes; (void)n_in; (void)out_size; (void)ws_size;
    const float* box = (const float*)d_in[2];
    const float* qf  = (const float*)d_in[3];
    const int* index = (const int*)d_in[5];
    const float* Wih = (const float*)d_in[6];
    const float* Whh = (const float*)d_in[7];
    const float* bih = (const float*)d_in[8];
    const float* bhh = (const float*)d_in[9];
    const float* Ww  = (const float*)d_in[10];
    const float* Wb  = (const float*)d_in[11];
    const float* Wpw = (const float*)d_in[12];
    const float* Wpb = (const float*)d_in[13];
    const float* fw  = (const float*)d_in[14];

    char* p = (char*)d_ws;
    short* Wstk = (short*)p;  p += (size_t)4096 * 1344 * 2;
    short* Wcat = (short*)p;  p += (size_t)1024 * 3072 * 2;
    short* xb   = (short*)p;  p += (size_t)14 * 256 * 320 * 2;
    short* hb0  = (short*)p;  p += (size_t)256 * 1024 * 2;
    short* hb1  = (short*)p;  p += (size_t)256 * 1024 * 2;
    float* c    = (float*)p;  p += (size_t)256 * 1024 * 4;
    float* lgt  = (float*)p;  p += (size_t)25600 * 4;

    hipMemsetAsync(hb0, 0, (size_t)256 * 1024 * 2, stream);
    hipMemsetAsync(c, 0, (size_t)256 * 1024 * 4, stream);
    hipMemsetAsync(lgt, 0, (size_t)25600 * 4, stream);

    prep_wstk<<<(4096 * 1344) / 256, 256, 0, stream>>>(Wih, Whh, bih, bhh, Wstk);
    prep_x<<<(14 * 256 * 320) / 256, 256, 0, stream>>>(qf, xb);
    prep_wcat<<<(1024 * 3072) / 256, 256, 0, stream>>>(Ww, Wpw, Wcat);

    short* hbuf[2] = {hb0, hb1};
    for (int t = 0; t < 14; ++t) {
        lstm_step<<<dim3(4, 64), 256, 0, stream>>>(
            xb + (size_t)t * 256 * 320, hbuf[t & 1], Wstk, c, hbuf[(t & 1) ^ 1]);
    }
    // after t=13 (reads hb1, writes hb0) the final hidden state is in hb0

    mlp_gemm<<<1600, 256, 0, stream>>>(box, hb0, Wcat, index, Wb, Wpb, fw, lgt);
    reduce_out<<<256, 128, 0, stream>>>(lgt, index, (float*)d_out);
}

// Round 3
// 399.600 us; speedup vs baseline: 1.5825x; 1.5579x over previous
//
#include <hip/hip_runtime.h>
#include <cstdint>
#include <cstddef>

#define DEVI __device__ __forceinline__

typedef __attribute__((ext_vector_type(8))) short short8;
typedef __attribute__((ext_vector_type(4))) float f32x4;
typedef __bf16 bf16x8 __attribute__((ext_vector_type(8)));

DEVI float sigf(float x) { return 1.0f / (1.0f + __expf(-x)); }
DEVI float tanh_f(float x) { return 2.0f / (1.0f + __expf(-2.0f * x)) - 1.0f; }

DEVI short f2bf(float x) {
    uint32_t u = __builtin_bit_cast(uint32_t, x);
    u += 0x7FFFu + ((u >> 16) & 1u);   // RTNE
    return (short)(u >> 16);
}

DEVI void gload16(const void* g, void* l) {
    __builtin_amdgcn_global_load_lds(
        (const __attribute__((address_space(1))) void*)g,
        (__attribute__((address_space(3))) void*)l, 16, 0, 0);
}

DEVI f32x4 mfma16(short8 a, short8 b, f32x4 c) {
    return __builtin_amdgcn_mfma_f32_16x16x32_bf16(
        __builtin_bit_cast(bf16x8, a), __builtin_bit_cast(bf16x8, b), c, 0, 0, 0);
}

// ---------------- prep kernels ----------------

// Wstk[n'][k], n' = hblk*64 + gate*16 + hl  (orig gate row = gate*1024 + hblk*16 + hl)
// k: [0,300)=W_ih, k==300 -> b_ih+b_hh (paired with constant-1.0 x column),
//    (300,320)=0, [320,1344)=W_hh
__global__ __launch_bounds__(256) void prep_wstk(const float* __restrict__ Wih,
                                                 const float* __restrict__ Whh,
                                                 const float* __restrict__ bih,
                                                 const float* __restrict__ bhh,
                                                 short* __restrict__ Wstk) {
    int idx = blockIdx.x * 256 + threadIdx.x;
    if (idx >= 4096 * 1344) return;
    int n = idx / 1344, k = idx - n * 1344;
    int hblk = n >> 6, gate = (n >> 4) & 3, hl = n & 15;
    int on = gate * 1024 + hblk * 16 + hl;
    float v = 0.f;
    if (k < 300) v = Wih[on * 300 + k];
    else if (k == 300) v = bih[on] + bhh[on];
    else if (k >= 320) v = Whh[on * 1024 + (k - 320)];
    Wstk[idx] = f2bf(v);
}

// x_bf16[t][b][e], e in [0,320): e<300 -> q, e==300 -> 1.0 (bias), else 0.
__global__ __launch_bounds__(256) void prep_x(const float* __restrict__ q,
                                              short* __restrict__ xb) {
    int idx = blockIdx.x * 256 + threadIdx.x;
    if (idx >= 14 * 256 * 320) return;
    int t = idx / (256 * 320);
    int r = idx - t * 256 * 320;
    int b = r / 320, e = r - b * 320;
    float v = (e < 300) ? q[(b * 14 + t) * 300 + e] : (e == 300 ? 1.0f : 0.0f);
    xb[idx] = f2bf(v);
}

// Wcat[n'][k], n' in [0,1024): hg=n'>>5, which=(n'>>4)&1, h=hg*16+(n'&15).
__global__ __launch_bounds__(256) void prep_wcat(const float* __restrict__ Ww,
                                                 const float* __restrict__ Wpw,
                                                 short* __restrict__ Wcat) {
    int idx = blockIdx.x * 256 + threadIdx.x;
    if (idx >= 1024 * 3072) return;
    int n = idx / 3072, k = idx - n * 3072;
    int hg = n >> 5, which = (n >> 4) & 1, hl = n & 15;
    int h = hg * 16 + hl;
    const float* src = which ? Wpw : Ww;
    Wcat[idx] = f2bf(src[h * 3072 + k]);
}

// exclusive prefix sum of index[256] -> cum[0..256], cum[256] = Mlive
__global__ __launch_bounds__(256) void prep_index(const int* __restrict__ index,
                                                  int* __restrict__ cum) {
    __shared__ int s[256];
    int t = threadIdx.x;
    s[t] = index[t];
    __syncthreads();
    for (int off = 1; off < 256; off <<= 1) {
        int v = (t >= off) ? s[t - off] : 0;
        __syncthreads();
        s[t] += v;
        __syncthreads();
    }
    cum[t + 1] = s[t];
    if (t == 0) cum[0] = 0;
}

// Compact live rows into Ac[dr][3072] bf16: cols [0,2048) = box row (f32->bf16),
// cols [2048,3072) = h[b]. dr = cum[b] + j. One block per original row.
__global__ __launch_bounds__(256) void compact_a(const float* __restrict__ box,
                                                 const short* __restrict__ hb,
                                                 const int* __restrict__ index,
                                                 const int* __restrict__ cum,
                                                 short* __restrict__ Ac) {
    int m = blockIdx.x;                  // 25600
    int b = m / 100, j = m - b * 100;
    if (j >= index[b]) return;
    size_t dr = (size_t)(cum[b] + j);
    int t = threadIdx.x;
    const float* src = box + (size_t)m * 2048 + t * 8;
    float4 v0 = *(const float4*)src;
    float4 v1 = *(const float4*)(src + 4);
    short8 s;
    s[0] = f2bf(v0.x); s[1] = f2bf(v0.y); s[2] = f2bf(v0.z); s[3] = f2bf(v0.w);
    s[4] = f2bf(v1.x); s[5] = f2bf(v1.y); s[6] = f2bf(v1.z); s[7] = f2bf(v1.w);
    *(short8*)&Ac[dr * 3072 + t * 8] = s;
    if (t < 128)
        *(short8*)&Ac[dr * 3072 + 2048 + t * 8] = *(const short8*)&hb[b * 1024 + t * 8];
}

// ---------------- fused LSTM step ----------------

// One timestep: gates = [x_t | h_in] @ Wstk^T, cell update fused in epilogue.
// 1D grid 256, XCD-pinned: each XCD owns 8 n-panels -> its 1.4 MB Wstk slice
// stays L2-resident across all 14 steps.
__global__ __launch_bounds__(256) void lstm_step(const short* __restrict__ xt,   // [256][320]
                                                 const short* __restrict__ hin,  // [256][1024]
                                                 const short* __restrict__ Wstk, // [4096][1344]
                                                 float* __restrict__ c,          // [256][1024]
                                                 short* __restrict__ hout) {
    __shared__ __attribute__((aligned(16))) short As[64 * 64];
    __shared__ __attribute__((aligned(16))) short Bs[64 * 64];
    const int tid = threadIdx.x, l = tid & 63, w = tid >> 6;
    const int bid = blockIdx.x;             // 256
    const int xcd = bid & 7, ii = bid >> 3;
    const int ny = xcd * 8 + (ii & 7);      // n-panel [0,64)
    const int mx = ii >> 3;                 // m-panel [0,4)
    const int m0 = mx * 64, n0 = ny * 64;

    f32x4 acc[4];
    for (int i = 0; i < 4; i++) acc[i] = f32x4{0.f, 0.f, 0.f, 0.f};

    for (int kt = 0; kt < 21; ++kt) {
        const int k0 = kt * 64;
        __syncthreads();
        for (int i = 0; i < 2; i++) {
            int r = w * 16 + i * 8 + (l >> 3);
            int cs = (l & 7) ^ (r & 7);
            const short* src;
            if (kt < 5) src = xt + (m0 + r) * 320 + (k0 + cs * 8);
            else        src = hin + (m0 + r) * 1024 + (k0 - 320 + cs * 8);
            gload16(src, &As[(w * 16 + i * 8) * 64]);
        }
        for (int i = 0; i < 2; i++) {
            int r = w * 16 + i * 8 + (l >> 3);
            int cs = (l & 7) ^ (r & 7);
            const short* src = Wstk + (size_t)(n0 + r) * 1344 + (k0 + cs * 8);
            gload16(src, &Bs[(w * 16 + i * 8) * 64]);
        }
        __syncthreads();
        for (int ks = 0; ks < 2; ++ks) {
            int m = w * 16 + (l & 15);
            int ca = (ks * 4 + (l >> 4)) ^ (m & 7);
            short8 a = *(const short8*)&As[m * 64 + ca * 8];
            for (int nf = 0; nf < 4; ++nf) {
                int n = nf * 16 + (l & 15);
                int cb = (ks * 4 + (l >> 4)) ^ (n & 7);
                short8 b = *(const short8*)&Bs[n * 64 + cb * 8];
                acc[nf] = mfma16(a, b, acc[nf]);
            }
        }
    }
    // epilogue: nf = gate (0:i 1:f 2:g 3:o), h = (n0/4) + (l&15)
    const int hl = l & 15, hi = l >> 4;
    const int h = (n0 >> 2) + hl;
    for (int rg = 0; rg < 4; ++rg) {
        int row = m0 + w * 16 + hi * 4 + rg;
        float ig = acc[0][rg], fg = acc[1][rg], gg = acc[2][rg], og = acc[3][rg];
        size_t off = (size_t)row * 1024 + h;
        float cn = sigf(fg) * c[off] + sigf(ig) * tanh_f(gg);
        c[off] = cn;
        hout[off] = f2bf(sigf(og) * tanh_f(cn));
    }
}

// ---------------- gated MLP (compacted, uniform, branch-free) ----------------

// C[Mlive][1024] = Ac @ Wcat^T, 128x128 tile, BK=64, 4 waves (2x2), acc 4x4.
// Pure global_load_lds staging (m97 structure). Epilogue fuses gated-MLP + f_w dot.
__global__ __launch_bounds__(256) void mlp_gemm(const short* __restrict__ Ac,   // [Mpad][3072]
                                                const short* __restrict__ Wcat, // [1024][3072]
                                                const int* __restrict__ mliveptr,
                                                const float* __restrict__ Wb,
                                                const float* __restrict__ Wpb,
                                                const float* __restrict__ fw,
                                                float* __restrict__ logits) {
    __shared__ __attribute__((aligned(16))) short As[128 * 64];
    __shared__ __attribute__((aligned(16))) short Bs[128 * 64];
    const int Mlive = *mliveptr;
    const int tid = threadIdx.x, l = tid & 63, w = tid >> 6;
    // XCD-balanced swizzle: live m-panels (low y) spread over all 8 XCDs;
    // a panel's 8 n-blocks are consecutive on one XCD.
    const int bid = blockIdx.x;              // 1600
    const int xcd = bid & 7, ii = bid >> 3;  // ii in [0,200)
    const int x = ii & 7, q = ii >> 3;       // q in [0,25)
    const int y = q * 8 + xcd;
    const int n0 = x * 128, m0 = y * 128;
    if (m0 >= Mlive) return;
    const int wm = w >> 1, wn = w & 1;

    const short* asrc[4];
    const short* bsrc[4];
    for (int i = 0; i < 4; i++) {
        int r = w * 32 + i * 8 + (l >> 3);
        int cs = (l & 7) ^ (r & 7);
        asrc[i] = Ac + (size_t)(m0 + r) * 3072 + cs * 8;
        bsrc[i] = Wcat + (size_t)(n0 + r) * 3072 + cs * 8;
    }

    f32x4 acc[4][4];
    for (int i = 0; i < 4; i++)
        for (int j = 0; j < 4; j++) acc[i][j] = f32x4{0.f, 0.f, 0.f, 0.f};

    for (int kt = 0; kt < 48; ++kt) {
        const int k0 = kt * 64;
        __syncthreads();
        for (int i = 0; i < 4; i++)
            gload16(asrc[i] + k0, &As[(w * 32 + i * 8) * 64]);
        for (int i = 0; i < 4; i++)
            gload16(bsrc[i] + k0, &Bs[(w * 32 + i * 8) * 64]);
        __syncthreads();
        for (int ks = 0; ks < 2; ++ks) {
            short8 a[4], b[4];
            for (int mf = 0; mf < 4; ++mf) {
                int m = wm * 64 + mf * 16 + (l & 15);
                int ca = (ks * 4 + (l >> 4)) ^ (m & 7);
                a[mf] = *(const short8*)&As[m * 64 + ca * 8];
            }
            for (int nf = 0; nf < 4; ++nf) {
                int n = wn * 64 + nf * 16 + (l & 15);
                int cb = (ks * 4 + (l >> 4)) ^ (n & 7);
                b[nf] = *(const short8*)&Bs[n * 64 + cb * 8];
            }
            for (int mf = 0; mf < 4; ++mf)
                for (int nf = 0; nf < 4; ++nf)
                    acc[mf][nf] = mfma16(a[mf], b[nf], acc[mf][nf]);
        }
    }

    const int hl = l & 15, hi = l >> 4;
    for (int mf = 0; mf < 4; ++mf) {
        float part[4] = {0.f, 0.f, 0.f, 0.f};
        for (int p = 0; p < 2; ++p) {
            int ntg = (n0 + wn * 64) / 16 + 2 * p;
            int hg = ntg >> 1;
            int h = hg * 16 + hl;
            float fwv = fw[h], wbv = Wb[h], wpbv = Wpb[h];
            for (int rg = 0; rg < 4; ++rg) {
                float y2 = tanh_f(acc[mf][2 * p][rg] + wbv);
                float g2 = sigf(acc[mf][2 * p + 1][rg] + wpbv);
                part[rg] += y2 * g2 * fwv;
            }
        }
        for (int rg = 0; rg < 4; ++rg) {
            float v = part[rg];
            v += __shfl_xor(v, 1, 64);
            v += __shfl_xor(v, 2, 64);
            v += __shfl_xor(v, 4, 64);
            v += __shfl_xor(v, 8, 64);
            if (hl == 0) {
                int row = m0 + wm * 64 + mf * 16 + hi * 4 + rg;
                atomicAdd(&logits[row], v);
            }
        }
    }
}

__global__ __launch_bounds__(128) void reduce_out(const float* __restrict__ logits,
                                                  const int* __restrict__ index,
                                                  const int* __restrict__ cum,
                                                  float* __restrict__ out) {
    int b = blockIdx.x, t = threadIdx.x;
    int idx = index[b];
    int base = cum[b];
    float v = 0.f;
    if (t < 100 && t < idx) v = sigf(logits[base + t]);
    for (int m = 32; m; m >>= 1) v += __shfl_down(v, m, 64);
    __shared__ float s[2];
    if ((t & 63) == 0) s[t >> 6] = v;
    __syncthreads();
    if (t == 0) out[b] = s[0] + s[1];
}

// ---------------- host ----------------

extern "C" void kernel_launch(void* const* d_in, const int* in_sizes, int n_in,
                              void* d_out, int out_size, void* d_ws, size_t ws_size,
                              hipStream_t stream) {
    (void)in_sizes; (void)n_in; (void)out_size; (void)ws_size;
    const float* box = (const float*)d_in[2];
    const float* qf  = (const float*)d_in[3];
    const int* index = (const int*)d_in[5];
    const float* Wih = (const float*)d_in[6];
    const float* Whh = (const float*)d_in[7];
    const float* bih = (const float*)d_in[8];
    const float* bhh = (const float*)d_in[9];
    const float* Ww  = (const float*)d_in[10];
    const float* Wb  = (const float*)d_in[11];
    const float* Wpw = (const float*)d_in[12];
    const float* Wpb = (const float*)d_in[13];
    const float* fw  = (const float*)d_in[14];

    char* p = (char*)d_ws;
    short* Wstk = (short*)p;  p += (size_t)4096 * 1344 * 2;
    short* Wcat = (short*)p;  p += (size_t)1024 * 3072 * 2;
    short* xb   = (short*)p;  p += (size_t)14 * 256 * 320 * 2;
    short* hb0  = (short*)p;  p += (size_t)256 * 1024 * 2;
    short* hb1  = (short*)p;  p += (size_t)256 * 1024 * 2;
    float* c    = (float*)p;  p += (size_t)256 * 1024 * 4;
    int*   cum  = (int*)p;    p += 260 * 4;
    float* lgt  = (float*)p;  p += (size_t)25600 * 4;
    p = (char*)(((uintptr_t)p + 255) & ~(uintptr_t)255);
    short* Ac   = (short*)p;  p += (size_t)25600 * 3072 * 2;   // ~157 MB

    hipMemsetAsync(hb0, 0, (size_t)256 * 1024 * 2, stream);
    hipMemsetAsync(c, 0, (size_t)256 * 1024 * 4, stream);
    hipMemsetAsync(lgt, 0, (size_t)25600 * 4, stream);

    prep_index<<<1, 256, 0, stream>>>(index, cum);
    prep_wstk<<<(4096 * 1344) / 256, 256, 0, stream>>>(Wih, Whh, bih, bhh, Wstk);
    prep_x<<<(14 * 256 * 320) / 256, 256, 0, stream>>>(qf, xb);
    prep_wcat<<<(1024 * 3072) / 256, 256, 0, stream>>>(Ww, Wpw, Wcat);

    short* hbuf[2] = {hb0, hb1};
    for (int t = 0; t < 14; ++t) {
        lstm_step<<<256, 256, 0, stream>>>(
            xb + (size_t)t * 256 * 320, hbuf[t & 1], Wstk, c, hbuf[(t & 1) ^ 1]);
    }
    // final hidden state in hb0

    compact_a<<<25600, 256, 0, stream>>>(box, hb0, index, cum, Ac);
    mlp_gemm<<<1600, 256, 0, stream>>>(Ac, Wcat, cum + 256, Wb, Wpb, fw, lgt);
    reduce_out<<<256, 128, 0, stream>>>(lgt, index, cum, (float*)d_out);
}